// Round 2
// baseline (146.277 us; speedup 1.0000x reference)
//
#include <hip/hip_runtime.h>

#define EPS 1e-7f
#define BATCH 8
#define NPT 2048   // points per batch
#define NFEAT 6
#define LOG2E 1.44269504088896340736f
#define RPB 8      // rows per block

typedef float vf4 __attribute__((ext_vector_type(4)));

// R2 DIAGNOSTIC PROBE — intentional, expected regression.
// The kernel never appears in rocprof top-5 (fills at 80-87us dominate), so
// its true duration is unknown: dur_us=141 is consistent BOTH with
// kernel~58us (store path at 2.3 TB/s, 37us opportunity) AND kernel~25us
// (near write roofline, remaining dur_us is harness fill+reset overhead).
// This probe stores every output line TWICE (pass 1 regular, pass 2
// nontemporal from saved registers; asm memory barrier prevents dead-store
// elimination of pass 1). Identical values -> still correct. The +134MB of
// writes either (a) pushes the kernel above the fills so we get its counter
// row, or (b) its continued absence from top-5 proves kernel < ~50us.
// Delta-dur_us also directly measures the store path's TB/s.
__global__ __launch_bounds__(512)
void wij_fused_kernel(const float* __restrict__ emb,
                      const float* __restrict__ alpha,
                      const float* __restrict__ beta,
                      const float* __restrict__ radius,
                      float* __restrict__ out) {
    __shared__ float spow[NPT];   // pow row for this batch
    __shared__ float sred[8];     // per-wave mins

    int blk = blockIdx.x;                      // 0 .. BATCH*NPT/RPB - 1
    int b  = blk >> 8;                         // / (NPT/RPB) = /256
    int n0 = (blk & 255) * RPB;

    const float* base = emb + (size_t)b * NFEAT * NPT;
    int t = threadIdx.x;

    // ---- pow + min (redundant per block, trivial cost) ----
    float a2 = 2.0f * alpha[0];
    vf4 pm = ((const vf4*)(base + 4 * NPT))[t];
    vf4 pw;
    pw.x = __builtin_amdgcn_exp2f(a2 * __log2f(pm.x));
    pw.y = __builtin_amdgcn_exp2f(a2 * __log2f(pm.y));
    pw.z = __builtin_amdgcn_exp2f(a2 * __log2f(pm.z));
    pw.w = __builtin_amdgcn_exp2f(a2 * __log2f(pm.w));
    ((vf4*)spow)[t] = pw;

    float lmin = fminf(fminf(pw.x, pw.y), fminf(pw.z, pw.w));
    for (int off = 32; off > 0; off >>= 1)
        lmin = fminf(lmin, __shfl_down(lmin, off, 64));
    if ((t & 63) == 0) sred[t >> 6] = lmin;
    __syncthreads();
    float dmin = fminf(fminf(fminf(sred[0], sred[1]), fminf(sred[2], sred[3])),
                       fminf(fminf(sred[4], sred[5]), fminf(sred[6], sred[7]))) + EPS;

    // ---- fold scalars: w = exp2(beff2 - cb * |c_n-c_m|^2 * min(pn,pm)) ----
    float r  = radius[0];
    float bt = beta[0];
    float beff2 = bt * bt * 1e-4f * LOG2E;           // beta^2/1e4 in base-2
    float cb = beff2 / (dmin * (r * r + EPS));       // one divide per thread, off hot path

    // ---- column fragments ----
    vf4 cx = ((const vf4*)(base + 1 * NPT))[t];
    vf4 cy = ((const vf4*)(base + 2 * NPT))[t];

    // ---- row scalars ----
    float xn[RPB], yn[RPB], pn[RPB];
    #pragma unroll
    for (int rI = 0; rI < RPB; ++rI) {
        xn[rI] = base[1 * NPT + n0 + rI];
        yn[rI] = base[2 * NPT + n0 + rI];
        pn[rI] = spow[n0 + rI];
    }

    vf4* outp = (vf4*)(out + (size_t)(b * NPT + n0) * NPT) + t;
    vf4 wsave[RPB];
    #pragma unroll
    for (int rI = 0; rI < RPB; ++rI) {
        vf4 w;
        {
            float dx = xn[rI] - cx.x, dy = yn[rI] - cy.x;
            float da = (dx * dx + dy * dy) * fminf(pn[rI], pw.x);
            w.x = __builtin_amdgcn_exp2f(beff2 - cb * da);
        }
        {
            float dx = xn[rI] - cx.y, dy = yn[rI] - cy.y;
            float da = (dx * dx + dy * dy) * fminf(pn[rI], pw.y);
            w.y = __builtin_amdgcn_exp2f(beff2 - cb * da);
        }
        {
            float dx = xn[rI] - cx.z, dy = yn[rI] - cy.z;
            float da = (dx * dx + dy * dy) * fminf(pn[rI], pw.z);
            w.z = __builtin_amdgcn_exp2f(beff2 - cb * da);
        }
        {
            float dx = xn[rI] - cx.w, dy = yn[rI] - cy.w;
            float da = (dx * dx + dy * dy) * fminf(pn[rI], pw.w);
            w.w = __builtin_amdgcn_exp2f(beff2 - cb * da);
        }
        wsave[rI] = w;
        outp[(size_t)rI * (NPT / 4)] = w;       // pass 1: regular store
    }

    // Compiler memory barrier: pass-1 stores must be treated as observable,
    // so dead-store elimination cannot remove them under the pass-2 overwrite.
    asm volatile("" ::: "memory");

    // pass 2: duplicate store of IDENTICAL values (diagnostic HBM write traffic)
    #pragma unroll
    for (int rI = 0; rI < RPB; ++rI)
        __builtin_nontemporal_store(wsave[rI], outp + (size_t)rI * (NPT / 4));
}

extern "C" void kernel_launch(void* const* d_in, const int* in_sizes, int n_in,
                              void* d_out, int out_size, void* d_ws, size_t ws_size,
                              hipStream_t stream) {
    const float* emb    = (const float*)d_in[0];
    const float* alpha  = (const float*)d_in[1];
    const float* beta   = (const float*)d_in[2];
    const float* radius = (const float*)d_in[3];
    float* out = (float*)d_out;
    (void)d_ws; (void)ws_size;

    wij_fused_kernel<<<(BATCH * NPT) / RPB, 512, 0, stream>>>(emb, alpha, beta, radius, out);
}